// Round 1
// baseline (1371.872 us; speedup 1.0000x reference)
//
#include <hip/hip_runtime.h>
#include <math.h>

#define TT 24
#define DM 128
#define DI 256
#define NTOK 207
#define EPSV 1e-5f

__device__ __forceinline__ float rlane(float v, int l) {
  return __int_as_float(__builtin_amdgcn_readlane(__float_as_int(v), l));
}
__device__ __forceinline__ float fsilu(float x) { return x * (1.f / (1.f + __expf(-x))); }
__device__ __forceinline__ float fsoftplus(float x) {
  return (x > 15.f) ? x : log1pf(__expf(x));
}

// GEMM: buf[t][c] = sum_k h_s[t][k] * W[c][k], t in [0,24), c in [0,256), K=128.
// thread -> (cg,tg): 8 cols, 3 rows. 256 threads cover it exactly.
__device__ __forceinline__ void gemm_h(const float* __restrict__ W,
                                       const float* __restrict__ h_s,
                                       float* __restrict__ bufp, int tid) {
  const int cg = tid & 31, tg = tid >> 5;
  const int c0 = cg * 8, t0 = tg * 3;
  float acc[3][8];
#pragma unroll
  for (int a = 0; a < 3; ++a)
#pragma unroll
    for (int b = 0; b < 8; ++b) acc[a][b] = 0.f;
  const float4* h4 = (const float4*)h_s;
#pragma unroll 4
  for (int j = 0; j < 32; ++j) {
    float4 hv[3];
#pragma unroll
    for (int a = 0; a < 3; ++a) hv[a] = h4[(t0 + a) * 32 + j];
#pragma unroll
    for (int b = 0; b < 8; ++b) {
      float4 w = *(const float4*)(W + (c0 + b) * DM + j * 4);
#pragma unroll
      for (int a = 0; a < 3; ++a) {
        acc[a][b] = fmaf(hv[a].x, w.x, acc[a][b]);
        acc[a][b] = fmaf(hv[a].y, w.y, acc[a][b]);
        acc[a][b] = fmaf(hv[a].z, w.z, acc[a][b]);
        acc[a][b] = fmaf(hv[a].w, w.w, acc[a][b]);
      }
    }
  }
#pragma unroll
  for (int a = 0; a < 3; ++a) {
    float4* dst = (float4*)(bufp + (t0 + a) * DI + c0);
    dst[0] = make_float4(acc[a][0], acc[a][1], acc[a][2], acc[a][3]);
    dst[1] = make_float4(acc[a][4], acc[a][5], acc[a][6], acc[a][7]);
  }
}

template <bool REV>
__device__ __forceinline__ void run_branch(
    const float* __restrict__ cw, const float* __restrict__ cb,
    const float* __restrict__ xw, const float* __restrict__ dw,
    const float* __restrict__ db, const float* __restrict__ Al,
    const float* __restrict__ Dp, const float (&xxr)[TT],
    const float (&szr)[TT], float (&yr)[TT], float* __restrict__ bufp,
    float* __restrict__ xd, int tid, int lane) {
  float cwr[4];
#pragma unroll
  for (int k = 0; k < 4; ++k) cwr[k] = cw[tid * 4 + k];
  const float cbd = cb[tid], dbd = db[tid], Dpd = Dp[tid];
  float dwr[8];
#pragma unroll
  for (int r = 0; r < 8; ++r) dwr[r] = dw[tid * 8 + r];
  float aa[16];
#pragma unroll
  for (int s = 0; s < 16; ++s) aa[s] = -__expf(Al[tid * 16 + s]);

  // depthwise causal conv (channel-local; REV handled via static re-index)
  float xcr[TT];
#pragma unroll
  for (int t = 0; t < TT; ++t) {
    float acc = cbd;
#pragma unroll
    for (int k = 0; k < 4; ++k) {
      const int j = t + k - 3;
      if (j >= 0) acc = fmaf(cwr[k], REV ? xxr[TT - 1 - j] : xxr[j], acc);
    }
    xcr[t] = fsilu(acc);
    bufp[t * DI + tid] = xcr[t];
  }
  __syncthreads();

  // x_dbl[t][e] = sum_d xc[t][d]*xw[e][d]; e-pairs x 8-way K split (160 threads)
  if (tid < 160) {
    const int pe = tid >> 3, q = tid & 7;
    const int e0 = pe * 2, e1 = e0 + 1;
    float a0[TT], a1[TT];
#pragma unroll
    for (int t = 0; t < TT; ++t) { a0[t] = 0.f; a1[t] = 0.f; }
    const float4* w0p = (const float4*)(xw + e0 * DI + q * 32);
    const float4* w1p = (const float4*)(xw + e1 * DI + q * 32);
#pragma unroll
    for (int jj = 0; jj < 8; ++jj) {
      float4 w0 = w0p[jj], w1 = w1p[jj];
#pragma unroll
      for (int t = 0; t < TT; ++t) {
        float4 v = ((const float4*)(bufp + t * DI + q * 32))[jj];
        a0[t] = fmaf(v.x, w0.x, a0[t]); a0[t] = fmaf(v.y, w0.y, a0[t]);
        a0[t] = fmaf(v.z, w0.z, a0[t]); a0[t] = fmaf(v.w, w0.w, a0[t]);
        a1[t] = fmaf(v.x, w1.x, a1[t]); a1[t] = fmaf(v.y, w1.y, a1[t]);
        a1[t] = fmaf(v.z, w1.z, a1[t]); a1[t] = fmaf(v.w, w1.w, a1[t]);
      }
    }
#pragma unroll
    for (int t = 0; t < TT; ++t) {
      float v0 = a0[t], v1 = a1[t];
      v0 += __shfl_xor(v0, 1, 64); v0 += __shfl_xor(v0, 2, 64); v0 += __shfl_xor(v0, 4, 64);
      v1 += __shfl_xor(v1, 1, 64); v1 += __shfl_xor(v1, 2, 64); v1 += __shfl_xor(v1, 4, 64);
      if (q == 0) { xd[t * 40 + e0] = v0; xd[t * 40 + e1] = v1; }
    }
  }
  __syncthreads();

  // selective scan; B/C/dt-row are wave-uniform -> readlane to SGPRs
  float hst[16];
#pragma unroll
  for (int s = 0; s < 16; ++s) hst[s] = 0.f;
#pragma unroll
  for (int t = 0; t < TT; ++t) {
    const float bc0 = xd[t * 40 + (lane & 31)];
    const float bc1 = xd[t * 40 + 32 + (lane & 7)];
    float dtraw = dbd;
#pragma unroll
    for (int r = 0; r < 8; ++r) dtraw = fmaf(rlane(bc0, r), dwr[r], dtraw);
    const float dt = fsoftplus(dtraw);
    const float u = xcr[t];
    const float dtu = dt * u;
    float yt = 0.f;
#pragma unroll
    for (int s = 0; s < 16; ++s) {
      const float Bs = rlane(bc0, 8 + s);
      const float Cs = (s < 8) ? rlane(bc0, 24 + s) : rlane(bc1, s - 8);
      const float ef = __expf(dt * aa[s]);
      hst[s] = fmaf(hst[s], ef, dtu * Bs);
      yt = fmaf(hst[s], Cs, yt);
    }
    yt = fmaf(Dpd, u, yt);
    const int ti = REV ? (TT - 1 - t) : t;
    yr[ti] = fmaf(yt, szr[ti], yr[ti]);
  }
  __syncthreads();
}

extern "C" __global__ __launch_bounds__(256) void bimamba(
    const float* __restrict__ x, const float* __restrict__ g1,
    const float* __restrict__ b1, const float* __restrict__ Win,
    const float* __restrict__ cwf, const float* __restrict__ cbf,
    const float* __restrict__ xwf, const float* __restrict__ dwf,
    const float* __restrict__ dbf, const float* __restrict__ Alf,
    const float* __restrict__ Dpf, const float* __restrict__ cwb,
    const float* __restrict__ cbb, const float* __restrict__ xwb,
    const float* __restrict__ dwb, const float* __restrict__ dbb,
    const float* __restrict__ Alb, const float* __restrict__ Dpb,
    const float* __restrict__ Wout, const float* __restrict__ g2,
    const float* __restrict__ b2, float* __restrict__ out) {
  __shared__ __align__(16) float h_s[TT * DM];   // 12 KB: LN1 out, later out_proj partial+o
  __shared__ __align__(16) float bufs[TT * DI];  // 24 KB: xz halves / xc / y
  __shared__ __align__(16) float xd_s[TT * 40];  // ~3.8 KB

  const int tid = threadIdx.x;
  const int lane = tid & 63, wv = tid >> 6;
  const int sq = blockIdx.x;
  const int bb = sq / NTOK, nn = sq % NTOK;
  const float* xbase = x + ((size_t)bb * TT * NTOK + nn) * DM;

  // ---- LN1 ----
#pragma unroll
  for (int i = 0; i < 6; ++i) {
    const int t = wv + 4 * i;
    const float* xr = xbase + (size_t)t * NTOK * DM;
    const float v0 = xr[lane], v1 = xr[lane + 64];
    float s1 = v0 + v1, s2 = v0 * v0 + v1 * v1;
#pragma unroll
    for (int off = 32; off; off >>= 1) {
      s1 += __shfl_xor(s1, off, 64);
      s2 += __shfl_xor(s2, off, 64);
    }
    const float m = s1 * (1.f / DM);
    const float r = rsqrtf(s2 * (1.f / DM) - m * m + EPSV);
    h_s[t * DM + lane] = (v0 - m) * r * g1[lane] + b1[lane];
    h_s[t * DM + lane + 64] = (v1 - m) * r * g1[lane + 64] + b1[lane + 64];
  }
  __syncthreads();

  // ---- in_proj (two halves), redistribute so thread d owns channel d ----
  gemm_h(Win, h_s, bufs, tid);
  __syncthreads();
  float xxr[TT];
#pragma unroll
  for (int t = 0; t < TT; ++t) xxr[t] = bufs[t * DI + tid];
  __syncthreads();
  gemm_h(Win + DI * DM, h_s, bufs, tid);
  __syncthreads();
  float szr[TT];
#pragma unroll
  for (int t = 0; t < TT; ++t) szr[t] = fsilu(bufs[t * DI + tid]);
  __syncthreads();

  float yr[TT];
#pragma unroll
  for (int t = 0; t < TT; ++t) yr[t] = 0.f;

  run_branch<false>(cwf, cbf, xwf, dwf, dbf, Alf, Dpf, xxr, szr, yr, bufs, xd_s, tid, lane);
  run_branch<true>(cwb, cbb, xwb, dwb, dbb, Alb, Dpb, xxr, szr, yr, bufs, xd_s, tid, lane);

#pragma unroll
  for (int t = 0; t < TT; ++t) bufs[t * DI + tid] = yr[t];
  __syncthreads();

  // ---- out_proj: o[t][c] = sum_d y[t][d]*Wout[c][d]; 2-way K split ----
  {
    const int cg = tid & 15, tg = (tid >> 4) & 7, kh = tid >> 7;
    const int c0 = cg * 8, t0 = tg * 3;
    float acc[3][8];
#pragma unroll
    for (int a = 0; a < 3; ++a)
#pragma unroll
      for (int b = 0; b < 8; ++b) acc[a][b] = 0.f;
    const float4* y4 = (const float4*)bufs;
#pragma unroll 4
    for (int j = 0; j < 32; ++j) {
      float4 yv[3];
#pragma unroll
      for (int a = 0; a < 3; ++a) yv[a] = y4[(t0 + a) * 64 + kh * 32 + j];
#pragma unroll
      for (int b = 0; b < 8; ++b) {
        float4 w = *(const float4*)(Wout + (c0 + b) * DI + kh * 128 + j * 4);
#pragma unroll
        for (int a = 0; a < 3; ++a) {
          acc[a][b] = fmaf(yv[a].x, w.x, acc[a][b]);
          acc[a][b] = fmaf(yv[a].y, w.y, acc[a][b]);
          acc[a][b] = fmaf(yv[a].z, w.z, acc[a][b]);
          acc[a][b] = fmaf(yv[a].w, w.w, acc[a][b]);
        }
      }
    }
    if (kh) {
#pragma unroll
      for (int a = 0; a < 3; ++a) {
        float4* dst = (float4*)(h_s + (t0 + a) * DM + c0);
        dst[0] = make_float4(acc[a][0], acc[a][1], acc[a][2], acc[a][3]);
        dst[1] = make_float4(acc[a][4], acc[a][5], acc[a][6], acc[a][7]);
      }
    }
    __syncthreads();
    if (!kh) {
#pragma unroll
      for (int a = 0; a < 3; ++a)
#pragma unroll
        for (int b = 0; b < 8; ++b)
          h_s[(t0 + a) * DM + c0 + b] += acc[a][b];
    }
  }
  __syncthreads();

  // ---- LN2 + residual ----
#pragma unroll
  for (int i = 0; i < 6; ++i) {
    const int t = wv + 4 * i;
    const float o0 = h_s[t * DM + lane], o1 = h_s[t * DM + lane + 64];
    float s1 = o0 + o1, s2 = o0 * o0 + o1 * o1;
#pragma unroll
    for (int off = 32; off; off >>= 1) {
      s1 += __shfl_xor(s1, off, 64);
      s2 += __shfl_xor(s2, off, 64);
    }
    const float m = s1 * (1.f / DM);
    const float r = rsqrtf(s2 * (1.f / DM) - m * m + EPSV);
    const float* xr = xbase + (size_t)t * NTOK * DM;
    float* orow = out + ((size_t)bb * TT + t) * NTOK * DM + (size_t)nn * DM;
    orow[lane] = (o0 - m) * r * g2[lane] + b2[lane] + xr[lane];
    orow[lane + 64] = (o1 - m) * r * g2[lane + 64] + b2[lane + 64] + xr[lane + 64];
  }
}

extern "C" void kernel_launch(void* const* d_in, const int* in_sizes, int n_in,
                              void* d_out, int out_size, void* d_ws, size_t ws_size,
                              hipStream_t stream) {
  bimamba<<<dim3(828), dim3(256), 0, stream>>>(
      (const float*)d_in[0], (const float*)d_in[1], (const float*)d_in[2],
      (const float*)d_in[3], (const float*)d_in[4], (const float*)d_in[5],
      (const float*)d_in[6], (const float*)d_in[7], (const float*)d_in[8],
      (const float*)d_in[9], (const float*)d_in[10], (const float*)d_in[11],
      (const float*)d_in[12], (const float*)d_in[13], (const float*)d_in[14],
      (const float*)d_in[15], (const float*)d_in[16], (const float*)d_in[17],
      (const float*)d_in[18], (const float*)d_in[19], (const float*)d_in[20],
      (float*)d_out);
}

// Round 2
// 724.143 us; speedup vs baseline: 1.8945x; 1.8945x over previous
//
#include <hip/hip_runtime.h>
#include <math.h>

#define TT 24
#define DM 128
#define DI 256
#define NTOK 207
#define EPSV 1e-5f
#define NSEQ 828

__device__ __forceinline__ float rlane(float v, int l) {
  return __int_as_float(__builtin_amdgcn_readlane(__float_as_int(v), l));
}
__device__ __forceinline__ float fsilu(float x) { return x * (1.f / (1.f + __expf(-x))); }
__device__ __forceinline__ float fsoftplus(float x) {
  return (x > 15.f) ? x : log1pf(__expf(x));
}

// ---------- transposed-weight GEMM (coalesced) ----------
// out[t][c] = sum_k h_s[t][k] * Wt[k][coff+c], Wt rows of length ldw.
// 256 thr = 64 c-groups (4 cols each) x 4 t-groups (6 rows each). K=128.
__device__ __forceinline__ void gemm_in_t(const float* __restrict__ Wt, int coff,
                                          const float* __restrict__ h_s,
                                          float* __restrict__ bufp, int tid) {
  const int cg = tid & 63, tg = tid >> 6;
  const int c0 = coff + cg * 4, t0 = tg * 6;
  float4 acc[6];
#pragma unroll
  for (int a = 0; a < 6; ++a) acc[a] = make_float4(0.f, 0.f, 0.f, 0.f);
  const float4* h4 = (const float4*)h_s;
#pragma unroll 2
  for (int j = 0; j < 32; ++j) {
    float4 hv[6];
#pragma unroll
    for (int a = 0; a < 6; ++a) hv[a] = h4[(t0 + a) * 32 + j];
#pragma unroll
    for (int x = 0; x < 4; ++x) {
      float4 w = *(const float4*)(Wt + (j * 4 + x) * 512 + c0);
#pragma unroll
      for (int a = 0; a < 6; ++a) {
        const float hx = (x == 0) ? hv[a].x : (x == 1) ? hv[a].y : (x == 2) ? hv[a].z : hv[a].w;
        acc[a].x = fmaf(hx, w.x, acc[a].x);
        acc[a].y = fmaf(hx, w.y, acc[a].y);
        acc[a].z = fmaf(hx, w.z, acc[a].z);
        acc[a].w = fmaf(hx, w.w, acc[a].w);
      }
    }
  }
#pragma unroll
  for (int a = 0; a < 6; ++a)
    *(float4*)(bufp + (t0 + a) * DI + (c0 - coff)) = acc[a];
}

// ---------- fallback (untransposed) GEMM, round-1 style ----------
__device__ __forceinline__ void gemm_h(const float* __restrict__ W,
                                       const float* __restrict__ h_s,
                                       float* __restrict__ bufp, int tid) {
  const int cg = tid & 31, tg = tid >> 5;
  const int c0 = cg * 8, t0 = tg * 3;
  float acc[3][8];
#pragma unroll
  for (int a = 0; a < 3; ++a)
#pragma unroll
    for (int b = 0; b < 8; ++b) acc[a][b] = 0.f;
  const float4* h4 = (const float4*)h_s;
#pragma unroll 4
  for (int j = 0; j < 32; ++j) {
    float4 hv[3];
#pragma unroll
    for (int a = 0; a < 3; ++a) hv[a] = h4[(t0 + a) * 32 + j];
#pragma unroll
    for (int b = 0; b < 8; ++b) {
      float4 w = *(const float4*)(W + (c0 + b) * DM + j * 4);
#pragma unroll
      for (int a = 0; a < 3; ++a) {
        acc[a][b] = fmaf(hv[a].x, w.x, acc[a][b]);
        acc[a][b] = fmaf(hv[a].y, w.y, acc[a][b]);
        acc[a][b] = fmaf(hv[a].z, w.z, acc[a][b]);
        acc[a][b] = fmaf(hv[a].w, w.w, acc[a][b]);
      }
    }
  }
#pragma unroll
  for (int a = 0; a < 3; ++a) {
    float4* dst = (float4*)(bufp + (t0 + a) * DI + c0);
    dst[0] = make_float4(acc[a][0], acc[a][1], acc[a][2], acc[a][3]);
    dst[1] = make_float4(acc[a][4], acc[a][5], acc[a][6], acc[a][7]);
  }
}

// ---------- one mamba branch: conv -> x_proj -> scan (raw y, no silu(z)) ----------
template <bool REV>
__device__ __forceinline__ void run_branch(
    const float* __restrict__ cw, const float* __restrict__ cb,
    const float* __restrict__ xw, const float* __restrict__ dw,
    const float* __restrict__ db, const float* __restrict__ Al,
    const float* __restrict__ Dp, float (&yr)[TT],
    const float* __restrict__ xx_s, float* __restrict__ xc_s,
    float* __restrict__ xd, int tid, int lane) {
  // depthwise causal conv, channel-local, sliding window (REV = static re-index)
  {
    float cwr[4];
#pragma unroll
    for (int k = 0; k < 4; ++k) cwr[k] = cw[tid * 4 + k];
    const float cbd = cb[tid];
    float xm3 = 0.f, xm2 = 0.f, xm1 = 0.f;
#pragma unroll
    for (int t = 0; t < TT; ++t) {
      const float xt = xx_s[(REV ? (TT - 1 - t) : t) * DI + tid];
      float acc = fmaf(cwr[0], xm3, cbd);
      acc = fmaf(cwr[1], xm2, acc);
      acc = fmaf(cwr[2], xm1, acc);
      acc = fmaf(cwr[3], xt, acc);
      xc_s[t * DI + tid] = fsilu(acc);
      xm3 = xm2; xm2 = xm1; xm1 = xt;
    }
  }
  __syncthreads();

  // x_dbl[t][e] = sum_d xc[t][d]*xw[e][d]; e-pairs x 8-way K split, t in chunks of 6
  if (tid < 160) {
    const int pe = tid >> 3, q = tid & 7;
    const float4* w0p = (const float4*)(xw + (2 * pe) * DI) + q * 8;
    const float4* w1p = (const float4*)(xw + (2 * pe + 1) * DI) + q * 8;
    const float4* xc4 = (const float4*)xc_s;
#pragma unroll
    for (int c = 0; c < 4; ++c) {
      float a0[6], a1[6];
#pragma unroll
      for (int i = 0; i < 6; ++i) { a0[i] = 0.f; a1[i] = 0.f; }
#pragma unroll
      for (int jj = 0; jj < 8; ++jj) {
        const float4 w0 = w0p[jj], w1 = w1p[jj];
#pragma unroll
        for (int i = 0; i < 6; ++i) {
          const float4 v = xc4[(c * 6 + i) * 64 + q * 8 + jj];
          a0[i] = fmaf(v.x, w0.x, a0[i]); a0[i] = fmaf(v.y, w0.y, a0[i]);
          a0[i] = fmaf(v.z, w0.z, a0[i]); a0[i] = fmaf(v.w, w0.w, a0[i]);
          a1[i] = fmaf(v.x, w1.x, a1[i]); a1[i] = fmaf(v.y, w1.y, a1[i]);
          a1[i] = fmaf(v.z, w1.z, a1[i]); a1[i] = fmaf(v.w, w1.w, a1[i]);
        }
      }
#pragma unroll
      for (int i = 0; i < 6; ++i) {
        float v0 = a0[i], v1 = a1[i];
        v0 += __shfl_xor(v0, 1, 64); v0 += __shfl_xor(v0, 2, 64); v0 += __shfl_xor(v0, 4, 64);
        v1 += __shfl_xor(v1, 1, 64); v1 += __shfl_xor(v1, 2, 64); v1 += __shfl_xor(v1, 4, 64);
        if (q == 0) {
          xd[(c * 6 + i) * 40 + 2 * pe] = v0;
          xd[(c * 6 + i) * 40 + 2 * pe + 1] = v1;
        }
      }
    }
  }
  __syncthreads();

  // selective scan; B/C/dt-row wave-uniform -> readlane
  {
    float dwr[8];
#pragma unroll
    for (int r = 0; r < 8; ++r) dwr[r] = dw[tid * 8 + r];
    const float dbd = db[tid], Dpd = Dp[tid];
    float aa[16];
#pragma unroll
    for (int s = 0; s < 16; ++s) aa[s] = -__expf(Al[tid * 16 + s]);
    float hst[16];
#pragma unroll
    for (int s = 0; s < 16; ++s) hst[s] = 0.f;
#pragma unroll
    for (int t = 0; t < TT; ++t) {
      const float bc0 = xd[t * 40 + (lane & 31)];
      const float bc1 = xd[t * 40 + 32 + (lane & 7)];
      float dtraw = dbd;
#pragma unroll
      for (int r = 0; r < 8; ++r) dtraw = fmaf(rlane(bc0, r), dwr[r], dtraw);
      const float dt = fsoftplus(dtraw);
      const float u = xc_s[t * DI + tid];
      const float dtu = dt * u;
      float yt = 0.f;
#pragma unroll
      for (int s = 0; s < 16; ++s) {
        const float Bs = rlane(bc0, 8 + s);
        const float Cs = (s < 8) ? rlane(bc0, 24 + s) : rlane(bc1, s - 8);
        const float ef = __expf(dt * aa[s]);
        hst[s] = fmaf(hst[s], ef, dtu * Bs);
        yt = fmaf(hst[s], Cs, yt);
      }
      yt = fmaf(Dpd, u, yt);
      yr[REV ? (TT - 1 - t) : t] += yt;
    }
  }
  __syncthreads();
}

template <bool TW>
__global__ __launch_bounds__(256) void bimamba(
    const float* __restrict__ x, const float* __restrict__ g1,
    const float* __restrict__ b1, const float* __restrict__ Win,
    const float* __restrict__ cwf, const float* __restrict__ cbf,
    const float* __restrict__ xwf, const float* __restrict__ dwf,
    const float* __restrict__ dbf, const float* __restrict__ Alf,
    const float* __restrict__ Dpf, const float* __restrict__ cwb,
    const float* __restrict__ cbb, const float* __restrict__ xwb,
    const float* __restrict__ dwb, const float* __restrict__ dbb,
    const float* __restrict__ Alb, const float* __restrict__ Dpb,
    const float* __restrict__ Wout, const float* __restrict__ g2,
    const float* __restrict__ b2, const float* __restrict__ wt,
    float* __restrict__ out) {
  __shared__ __align__(16) float h_s[TT * DM];   // 12KB: LN1 out -> xd (960 f) -> out_proj o
  __shared__ __align__(16) float xx_s[TT * DI];  // 24KB: z-half then xx-half of in_proj
  __shared__ __align__(16) float xc_s[TT * DI];  // 24KB: conv out per branch -> final y*silu(z)

  const int tid = threadIdx.x;
  const int lane = tid & 63, wv = tid >> 6;
  const int sq = blockIdx.x;
  const int bb = sq / NTOK, nn = sq % NTOK;
  const float* xbase = x + ((size_t)bb * TT * NTOK + nn) * DM;

  // ---- LN1 ----
#pragma unroll
  for (int i = 0; i < 6; ++i) {
    const int t = wv + 4 * i;
    const float* xr = xbase + (size_t)t * NTOK * DM;
    const float v0 = xr[lane], v1 = xr[lane + 64];
    float s1 = v0 + v1, s2 = v0 * v0 + v1 * v1;
#pragma unroll
    for (int off = 32; off; off >>= 1) {
      s1 += __shfl_xor(s1, off, 64);
      s2 += __shfl_xor(s2, off, 64);
    }
    const float m = s1 * (1.f / DM);
    const float r = rsqrtf(s2 * (1.f / DM) - m * m + EPSV);
    h_s[t * DM + lane] = (v0 - m) * r * g1[lane] + b1[lane];
    h_s[t * DM + lane + 64] = (v1 - m) * r * g1[lane + 64] + b1[lane + 64];
  }
  __syncthreads();

  // ---- in_proj: z half first (-> szr regs), then xx half stays in xx_s ----
  if (TW) gemm_in_t(wt, 256, h_s, xx_s, tid); else gemm_h(Win + DI * DM, h_s, xx_s, tid);
  __syncthreads();
  float szr[TT];
#pragma unroll
  for (int t = 0; t < TT; ++t) szr[t] = fsilu(xx_s[t * DI + tid]);
  __syncthreads();
  if (TW) gemm_in_t(wt, 0, h_s, xx_s, tid); else gemm_h(Win, h_s, xx_s, tid);
  __syncthreads();

  float yr[TT];
#pragma unroll
  for (int t = 0; t < TT; ++t) yr[t] = 0.f;
  float* xd = h_s;  // h_s free after in_proj; 960 floats needed

  run_branch<false>(cwf, cbf, xwf, dwf, dbf, Alf, Dpf, yr, xx_s, xc_s, xd, tid, lane);
  run_branch<true>(cwb, cbb, xwb, dwb, dbb, Alb, Dpb, yr, xx_s, xc_s, xd, tid, lane);

  // ---- y_total = (y_f + y_b_rev) * silu(z), staged to LDS for out_proj ----
#pragma unroll
  for (int t = 0; t < TT; ++t) xc_s[t * DI + tid] = yr[t] * szr[t];
  __syncthreads();

  // ---- out_proj: o[t][c] = sum_d y[t][d]*Wout[c][d]; 2-way K split ----
  if (TW) {
    const float* Wt_out = wt + 512 * 128;  // [256][128]
    const int cg = tid & 31, tg = (tid >> 5) & 3, kh = tid >> 7;
    const int c0 = cg * 4, t0 = tg * 6;
    float4 acc[6];
#pragma unroll
    for (int a = 0; a < 6; ++a) acc[a] = make_float4(0.f, 0.f, 0.f, 0.f);
    const float4* y4 = (const float4*)xc_s;
#pragma unroll 2
    for (int j = 0; j < 32; ++j) {
      float4 yv[6];
#pragma unroll
      for (int a = 0; a < 6; ++a) yv[a] = y4[(t0 + a) * 64 + kh * 32 + j];
#pragma unroll
      for (int x = 0; x < 4; ++x) {
        float4 w = *(const float4*)(Wt_out + (kh * 128 + j * 4 + x) * 128 + c0);
#pragma unroll
        for (int a = 0; a < 6; ++a) {
          const float yx = (x == 0) ? yv[a].x : (x == 1) ? yv[a].y : (x == 2) ? yv[a].z : yv[a].w;
          acc[a].x = fmaf(yx, w.x, acc[a].x);
          acc[a].y = fmaf(yx, w.y, acc[a].y);
          acc[a].z = fmaf(yx, w.z, acc[a].z);
          acc[a].w = fmaf(yx, w.w, acc[a].w);
        }
      }
    }
    if (kh) {
#pragma unroll
      for (int a = 0; a < 6; ++a) *(float4*)(h_s + (t0 + a) * DM + c0) = acc[a];
    }
    __syncthreads();
    if (!kh) {
#pragma unroll
      for (int a = 0; a < 6; ++a) {
        float4* p = (float4*)(h_s + (t0 + a) * DM + c0);
        float4 o = *p;
        o.x += acc[a].x; o.y += acc[a].y; o.z += acc[a].z; o.w += acc[a].w;
        *p = o;
      }
    }
  } else {
    const int cg = tid & 15, tg = (tid >> 4) & 7, kh = tid >> 7;
    const int c0 = cg * 8, t0 = tg * 3;
    float acc[3][8];
#pragma unroll
    for (int a = 0; a < 3; ++a)
#pragma unroll
      for (int b = 0; b < 8; ++b) acc[a][b] = 0.f;
    const float4* y4 = (const float4*)xc_s;
#pragma unroll 4
    for (int j = 0; j < 32; ++j) {
      float4 yv[3];
#pragma unroll
      for (int a = 0; a < 3; ++a) yv[a] = y4[(t0 + a) * 64 + kh * 32 + j];
#pragma unroll
      for (int b = 0; b < 8; ++b) {
        float4 w = *(const float4*)(Wout + (c0 + b) * DI + kh * 128 + j * 4);
#pragma unroll
        for (int a = 0; a < 3; ++a) {
          acc[a][b] = fmaf(yv[a].x, w.x, acc[a][b]);
          acc[a][b] = fmaf(yv[a].y, w.y, acc[a][b]);
          acc[a][b] = fmaf(yv[a].z, w.z, acc[a][b]);
          acc[a][b] = fmaf(yv[a].w, w.w, acc[a][b]);
        }
      }
    }
    if (kh) {
#pragma unroll
      for (int a = 0; a < 3; ++a) {
        float4* dst = (float4*)(h_s + (t0 + a) * DM + c0);
        dst[0] = make_float4(acc[a][0], acc[a][1], acc[a][2], acc[a][3]);
        dst[1] = make_float4(acc[a][4], acc[a][5], acc[a][6], acc[a][7]);
      }
    }
    __syncthreads();
    if (!kh) {
#pragma unroll
      for (int a = 0; a < 3; ++a)
#pragma unroll
        for (int b = 0; b < 8; ++b) h_s[(t0 + a) * DM + c0 + b] += acc[a][b];
    }
  }
  __syncthreads();

  // ---- LN2 + residual ----
#pragma unroll
  for (int i = 0; i < 6; ++i) {
    const int t = wv + 4 * i;
    const float o0 = h_s[t * DM + lane], o1 = h_s[t * DM + lane + 64];
    float s1 = o0 + o1, s2 = o0 * o0 + o1 * o1;
#pragma unroll
    for (int off = 32; off; off >>= 1) {
      s1 += __shfl_xor(s1, off, 64);
      s2 += __shfl_xor(s2, off, 64);
    }
    const float m = s1 * (1.f / DM);
    const float r = rsqrtf(s2 * (1.f / DM) - m * m + EPSV);
    const float* xr = xbase + (size_t)t * NTOK * DM;
    float* orow = out + (((size_t)bb * TT + t) * NTOK + nn) * DM;
    orow[lane] = (o0 - m) * r * g2[lane] + b2[lane] + xr[lane];
    orow[lane + 64] = (o1 - m) * r * g2[lane + 64] + b2[lane + 64] + xr[lane + 64];
  }
}

// one-shot weight transpose into workspace (coalesced writes, scattered reads)
__global__ void transpose_w(const float* __restrict__ Wi, const float* __restrict__ Wo,
                            float* __restrict__ wt) {
  const int i = blockIdx.x * 256 + threadIdx.x;
  // Wt_in [128][512] <- Win [512][128]
  if (i < 512 * 128) {
    const int r = i & 511, c = i >> 9;
    wt[i] = Wi[r * 128 + c];
  }
  // Wt_out [256][128] <- Wout [128][256]
  if (i < 256 * 128) {
    const int d = i >> 7, r = i & 127;
    wt[512 * 128 + i] = Wo[r * 256 + d];
  }
}

extern "C" void kernel_launch(void* const* d_in, const int* in_sizes, int n_in,
                              void* d_out, int out_size, void* d_ws, size_t ws_size,
                              hipStream_t stream) {
  const bool tw = ws_size >= (size_t)(512 * 128 + 256 * 128) * sizeof(float);
  if (tw) {
    transpose_w<<<dim3(256), dim3(256), 0, stream>>>(
        (const float*)d_in[3], (const float*)d_in[18], (float*)d_ws);
    bimamba<true><<<dim3(NSEQ), dim3(256), 0, stream>>>(
        (const float*)d_in[0], (const float*)d_in[1], (const float*)d_in[2],
        (const float*)d_in[3], (const float*)d_in[4], (const float*)d_in[5],
        (const float*)d_in[6], (const float*)d_in[7], (const float*)d_in[8],
        (const float*)d_in[9], (const float*)d_in[10], (const float*)d_in[11],
        (const float*)d_in[12], (const float*)d_in[13], (const float*)d_in[14],
        (const float*)d_in[15], (const float*)d_in[16], (const float*)d_in[17],
        (const float*)d_in[18], (const float*)d_in[19], (const float*)d_in[20],
        (const float*)d_ws, (float*)d_out);
  } else {
    bimamba<false><<<dim3(NSEQ), dim3(256), 0, stream>>>(
        (const float*)d_in[0], (const float*)d_in[1], (const float*)d_in[2],
        (const float*)d_in[3], (const float*)d_in[4], (const float*)d_in[5],
        (const float*)d_in[6], (const float*)d_in[7], (const float*)d_in[8],
        (const float*)d_in[9], (const float*)d_in[10], (const float*)d_in[11],
        (const float*)d_in[12], (const float*)d_in[13], (const float*)d_in[14],
        (const float*)d_in[15], (const float*)d_in[16], (const float*)d_in[17],
        (const float*)d_in[18], (const float*)d_in[19], (const float*)d_in[20],
        nullptr, (float*)d_out);
  }
}

// Round 3
// 210.010 us; speedup vs baseline: 6.5324x; 3.4481x over previous
//
#include <hip/hip_runtime.h>
#include <math.h>

#define TT 24
#define DM 128
#define DI 256
#define NTOK 207
#define EPSV 1e-5f
#define NSEQ 828

typedef unsigned short u16;
typedef unsigned int u32;

__device__ __forceinline__ float rlane(float v, int l) {
  return __int_as_float(__builtin_amdgcn_readlane(__float_as_int(v), l));
}
__device__ __forceinline__ float fsilu(float x) { return x * (1.f / (1.f + __expf(-x))); }
__device__ __forceinline__ float fsoftplus(float x) {
  return (x > 15.f) ? x : log1pf(__expf(x));
}
__device__ __forceinline__ u16 f2b(float f) {  // RNE bf16
  u32 u = __float_as_uint(f);
  u += 0x7fffu + ((u >> 16) & 1u);
  return (u16)(u >> 16);
}
__device__ __forceinline__ float b2f(u16 h) { return __uint_as_float(((u32)h) << 16); }

// ---- in_proj GEMM, transposed weights (coalesced): out[t][c]=sum_k h[t][k]*Wt[k][coff+c]
template <bool SIL>
__device__ __forceinline__ void gemm_in_t(const float* __restrict__ Wt, int coff,
                                          const float* __restrict__ h_s,
                                          u16* __restrict__ bufp, int tid) {
  const int cg = tid & 63, tg = tid >> 6;
  const int c0 = coff + cg * 4, t0 = tg * 6;
  float4 acc[6];
#pragma unroll
  for (int a = 0; a < 6; ++a) acc[a] = make_float4(0.f, 0.f, 0.f, 0.f);
  const float4* h4 = (const float4*)h_s;
#pragma unroll 2
  for (int j = 0; j < 32; ++j) {
    float4 hv[6];
#pragma unroll
    for (int a = 0; a < 6; ++a) hv[a] = h4[(t0 + a) * 32 + j];
#pragma unroll
    for (int x = 0; x < 4; ++x) {
      float4 w = *(const float4*)(Wt + (j * 4 + x) * 512 + c0);
#pragma unroll
      for (int a = 0; a < 6; ++a) {
        const float hx = (x == 0) ? hv[a].x : (x == 1) ? hv[a].y : (x == 2) ? hv[a].z : hv[a].w;
        acc[a].x = fmaf(hx, w.x, acc[a].x);
        acc[a].y = fmaf(hx, w.y, acc[a].y);
        acc[a].z = fmaf(hx, w.z, acc[a].z);
        acc[a].w = fmaf(hx, w.w, acc[a].w);
      }
    }
  }
#pragma unroll
  for (int a = 0; a < 6; ++a) {
    float4 v = acc[a];
    if (SIL) { v.x = fsilu(v.x); v.y = fsilu(v.y); v.z = fsilu(v.z); v.w = fsilu(v.w); }
    ushort4 o;
    o.x = f2b(v.x); o.y = f2b(v.y); o.z = f2b(v.z); o.w = f2b(v.w);
    *(ushort4*)(bufp + (t0 + a) * DI + cg * 4) = o;
  }
}

// ---- fallback in_proj GEMM (untransposed weights)
template <bool SIL>
__device__ __forceinline__ void gemm_h(const float* __restrict__ W,
                                       const float* __restrict__ h_s,
                                       u16* __restrict__ bufp, int tid) {
  const int cg = tid & 31, tg = tid >> 5;
  const int c0 = cg * 8, t0 = tg * 3;
  float acc[3][8];
#pragma unroll
  for (int a = 0; a < 3; ++a)
#pragma unroll
    for (int b = 0; b < 8; ++b) acc[a][b] = 0.f;
  const float4* h4 = (const float4*)h_s;
#pragma unroll 4
  for (int j = 0; j < 32; ++j) {
    float4 hv[3];
#pragma unroll
    for (int a = 0; a < 3; ++a) hv[a] = h4[(t0 + a) * 32 + j];
#pragma unroll
    for (int b = 0; b < 8; ++b) {
      float4 w = *(const float4*)(W + (c0 + b) * DM + j * 4);
#pragma unroll
      for (int a = 0; a < 3; ++a) {
        acc[a][b] = fmaf(hv[a].x, w.x, acc[a][b]);
        acc[a][b] = fmaf(hv[a].y, w.y, acc[a][b]);
        acc[a][b] = fmaf(hv[a].z, w.z, acc[a][b]);
        acc[a][b] = fmaf(hv[a].w, w.w, acc[a][b]);
      }
    }
  }
#pragma unroll
  for (int a = 0; a < 3; ++a) {
    ushort4 o0, o1;
    float v;
    v = SIL ? fsilu(acc[a][0]) : acc[a][0]; o0.x = f2b(v);
    v = SIL ? fsilu(acc[a][1]) : acc[a][1]; o0.y = f2b(v);
    v = SIL ? fsilu(acc[a][2]) : acc[a][2]; o0.z = f2b(v);
    v = SIL ? fsilu(acc[a][3]) : acc[a][3]; o0.w = f2b(v);
    v = SIL ? fsilu(acc[a][4]) : acc[a][4]; o1.x = f2b(v);
    v = SIL ? fsilu(acc[a][5]) : acc[a][5]; o1.y = f2b(v);
    v = SIL ? fsilu(acc[a][6]) : acc[a][6]; o1.z = f2b(v);
    v = SIL ? fsilu(acc[a][7]) : acc[a][7]; o1.w = f2b(v);
    *(ushort4*)(bufp + (t0 + a) * DI + c0) = o0;
    *(ushort4*)(bufp + (t0 + a) * DI + c0 + 4) = o1;
  }
}

// ---- one branch: conv -> x_proj -> scan. All per-t state in LDS.
template <bool REV>
__device__ __forceinline__ void run_branch(
    const float* __restrict__ cw, const float* __restrict__ cb,
    const float* __restrict__ xw, const float* __restrict__ dw,
    const float* __restrict__ db, const float* __restrict__ Al,
    const float* __restrict__ Dp, const u16* __restrict__ xx_s,
    u16* __restrict__ xc_s, const u16* __restrict__ sz_s,
    float* __restrict__ y_s, float* __restrict__ xd, int tid, int lane) {
  // depthwise causal conv (channel-local; REV = re-indexed read)
  {
    float cwr[4];
#pragma unroll
    for (int k = 0; k < 4; ++k) cwr[k] = cw[tid * 4 + k];
    const float cbd = cb[tid];
    float xm3 = 0.f, xm2 = 0.f, xm1 = 0.f;
#pragma unroll 4
    for (int t = 0; t < TT; ++t) {
      const float xt = b2f(xx_s[(REV ? (TT - 1 - t) : t) * DI + tid]);
      float acc = fmaf(cwr[0], xm3, cbd);
      acc = fmaf(cwr[1], xm2, acc);
      acc = fmaf(cwr[2], xm1, acc);
      acc = fmaf(cwr[3], xt, acc);
      xc_s[t * DI + tid] = f2b(fsilu(acc));
      xm3 = xm2; xm2 = xm1; xm1 = xt;
    }
  }
  __syncthreads();

  // x_dbl[t][e] = sum_d xc[t][d]*xw[e][d]; e-pairs x 8-way K split; jx rotation
  // (jj ^ ((q>>1)&3)) makes concurrent q-groups hit distinct LDS bank quads.
  if (tid < 160) {
    const int pe = tid >> 3, q = tid & 7;
    const float* w0 = xw + (2 * pe) * DI;
    const float* w1 = w0 + DI;
    const int rot = (q >> 1) & 3;
#pragma unroll
    for (int c = 0; c < 4; ++c) {
      float a0[6], a1[6];
#pragma unroll
      for (int i = 0; i < 6; ++i) { a0[i] = 0.f; a1[i] = 0.f; }
#pragma unroll
      for (int jj = 0; jj < 4; ++jj) {
        const int jx = jj ^ rot;
        const int dbase = q * 32 + jx * 8;
        const float4 wa0 = *(const float4*)(w0 + dbase);
        const float4 wb0 = *(const float4*)(w0 + dbase + 4);
        const float4 wa1 = *(const float4*)(w1 + dbase);
        const float4 wb1 = *(const float4*)(w1 + dbase + 4);
#pragma unroll
        for (int i = 0; i < 6; ++i) {
          const uint4 vv = *(const uint4*)(xc_s + (c * 6 + i) * DI + dbase);
          const float e0 = __uint_as_float(vv.x << 16);
          const float e1 = __uint_as_float(vv.x & 0xffff0000u);
          const float e2 = __uint_as_float(vv.y << 16);
          const float e3 = __uint_as_float(vv.y & 0xffff0000u);
          const float e4 = __uint_as_float(vv.z << 16);
          const float e5 = __uint_as_float(vv.z & 0xffff0000u);
          const float e6 = __uint_as_float(vv.w << 16);
          const float e7 = __uint_as_float(vv.w & 0xffff0000u);
          a0[i] = fmaf(e0, wa0.x, a0[i]); a0[i] = fmaf(e1, wa0.y, a0[i]);
          a0[i] = fmaf(e2, wa0.z, a0[i]); a0[i] = fmaf(e3, wa0.w, a0[i]);
          a0[i] = fmaf(e4, wb0.x, a0[i]); a0[i] = fmaf(e5, wb0.y, a0[i]);
          a0[i] = fmaf(e6, wb0.z, a0[i]); a0[i] = fmaf(e7, wb0.w, a0[i]);
          a1[i] = fmaf(e0, wa1.x, a1[i]); a1[i] = fmaf(e1, wa1.y, a1[i]);
          a1[i] = fmaf(e2, wa1.z, a1[i]); a1[i] = fmaf(e3, wa1.w, a1[i]);
          a1[i] = fmaf(e4, wb1.x, a1[i]); a1[i] = fmaf(e5, wb1.y, a1[i]);
          a1[i] = fmaf(e6, wb1.z, a1[i]); a1[i] = fmaf(e7, wb1.w, a1[i]);
        }
      }
#pragma unroll
      for (int i = 0; i < 6; ++i) {
        float v0 = a0[i], v1 = a1[i];
        v0 += __shfl_xor(v0, 1, 64); v0 += __shfl_xor(v0, 2, 64); v0 += __shfl_xor(v0, 4, 64);
        v1 += __shfl_xor(v1, 1, 64); v1 += __shfl_xor(v1, 2, 64); v1 += __shfl_xor(v1, 4, 64);
        if (q == 0) {
          xd[(c * 6 + i) * 40 + 2 * pe] = v0;
          xd[(c * 6 + i) * 40 + 2 * pe + 1] = v1;
        }
      }
    }
  }
  __syncthreads();

  // selective scan; per-t broadcast values via readlane; y straight to LDS
  {
    float dwr[8];
#pragma unroll
    for (int r = 0; r < 8; ++r) dwr[r] = dw[tid * 8 + r];
    const float dbd = db[tid], Dpd = Dp[tid];
    float aa[16];
#pragma unroll
    for (int s = 0; s < 16; ++s) aa[s] = -__expf(Al[tid * 16 + s]);
    float hst[16];
#pragma unroll
    for (int s = 0; s < 16; ++s) hst[s] = 0.f;
#pragma unroll 4
    for (int t = 0; t < TT; ++t) {
      const float bc0 = xd[t * 40 + (lane & 31)];
      const float bc1 = xd[t * 40 + 32 + (lane & 7)];
      float dtraw = dbd;
#pragma unroll
      for (int r = 0; r < 8; ++r) dtraw = fmaf(rlane(bc0, r), dwr[r], dtraw);
      const float dt = fsoftplus(dtraw);
      const float u = b2f(xc_s[t * DI + tid]);
      const float dtu = dt * u;
      float yt = 0.f;
#pragma unroll
      for (int s = 0; s < 16; ++s) {
        const float Bs = rlane(bc0, 8 + s);
        const float Cs = (s < 8) ? rlane(bc0, 24 + s) : rlane(bc1, s - 8);
        const float ef = __expf(dt * aa[s]);
        hst[s] = fmaf(hst[s], ef, dtu * Bs);
        yt = fmaf(hst[s], Cs, yt);
      }
      yt = fmaf(Dpd, u, yt);
      const int ti = REV ? (TT - 1 - t) : t;
      if (REV)
        y_s[ti * DI + tid] = (y_s[ti * DI + tid] + yt) * b2f(sz_s[ti * DI + tid]);
      else
        y_s[ti * DI + tid] = yt;
    }
  }
  __syncthreads();
}

template <bool TW>
__global__ __launch_bounds__(256) void bimamba(
    const float* __restrict__ x, const float* __restrict__ g1,
    const float* __restrict__ b1, const float* __restrict__ Win,
    const float* __restrict__ cwf, const float* __restrict__ cbf,
    const float* __restrict__ xwf, const float* __restrict__ dwf,
    const float* __restrict__ dbf, const float* __restrict__ Alf,
    const float* __restrict__ Dpf, const float* __restrict__ cwb,
    const float* __restrict__ cbb, const float* __restrict__ xwb,
    const float* __restrict__ dwb, const float* __restrict__ dbb,
    const float* __restrict__ Alb, const float* __restrict__ Dpb,
    const float* __restrict__ Wout, const float* __restrict__ g2,
    const float* __restrict__ b2, const float* __restrict__ wt,
    float* __restrict__ out) {
  __shared__ __align__(16) float h_s[TT * DM];  // 12KB: LN1 out -> xd(960f) -> o
  __shared__ __align__(16) u16 xx_s[TT * DI];   // 12KB bf16: x-half of in_proj
  __shared__ __align__(16) u16 xc_s[TT * DI];   // 12KB bf16: conv out (per branch)
  __shared__ __align__(16) u16 sz_s[TT * DI];   // 12KB bf16: silu(z)
  __shared__ __align__(16) float y_s[TT * DI];  // 24KB fp32: y accum -> y*sz

  const int tid = threadIdx.x;
  const int lane = tid & 63, wv = tid >> 6;
  const int sq = blockIdx.x;
  const int bb = sq / NTOK, nn = sq % NTOK;
  const float* xbase = x + ((size_t)bb * TT * NTOK + nn) * DM;

  // ---- LN1 ----
#pragma unroll
  for (int i = 0; i < 6; ++i) {
    const int t = wv + 4 * i;
    const float* xr = xbase + (size_t)t * NTOK * DM;
    const float v0 = xr[lane], v1 = xr[lane + 64];
    float s1 = v0 + v1, s2 = v0 * v0 + v1 * v1;
#pragma unroll
    for (int off = 32; off; off >>= 1) {
      s1 += __shfl_xor(s1, off, 64);
      s2 += __shfl_xor(s2, off, 64);
    }
    const float m = s1 * (1.f / DM);
    const float r = rsqrtf(s2 * (1.f / DM) - m * m + EPSV);
    h_s[t * DM + lane] = (v0 - m) * r * g1[lane] + b1[lane];
    h_s[t * DM + lane + 64] = (v1 - m) * r * g1[lane + 64] + b1[lane + 64];
  }
  __syncthreads();

  // ---- in_proj: z half -> sz_s (silu applied), x half -> xx_s ----
  if (TW) {
    gemm_in_t<true>(wt, 256, h_s, sz_s, tid);
    gemm_in_t<false>(wt, 0, h_s, xx_s, tid);
  } else {
    gemm_h<true>(Win + DI * DM, h_s, sz_s, tid);
    gemm_h<false>(Win, h_s, xx_s, tid);
  }
  __syncthreads();

  float* xd = h_s;  // h dead after in_proj; 960 floats reused per branch

  run_branch<false>(cwf, cbf, xwf, dwf, dbf, Alf, Dpf, xx_s, xc_s, sz_s, y_s, xd, tid, lane);
  run_branch<true>(cwb, cbb, xwb, dwb, dbb, Alb, Dpb, xx_s, xc_s, sz_s, y_s, xd, tid, lane);
  // y_s now holds (y_f + y_b_rev) * silu(z)

  // ---- out_proj: o[t][c] = sum_d y[t][d]*Wout[c][d]; 2-way K split ----
  if (TW) {
    const float* Wt_out = wt + 512 * 128;  // [256][128]: Wt_out[d][c] = Wout[c][d]
    const int cg = tid & 31, tg = (tid >> 5) & 3, kh = tid >> 7;
    const int c0 = cg * 4, t0 = tg * 6;
    float4 acc[6];
#pragma unroll
    for (int a = 0; a < 6; ++a) acc[a] = make_float4(0.f, 0.f, 0.f, 0.f);
    const float4* y4 = (const float4*)y_s;
#pragma unroll 2
    for (int j = 0; j < 32; ++j) {
      float4 yv[6];
#pragma unroll
      for (int a = 0; a < 6; ++a) yv[a] = y4[(t0 + a) * 64 + kh * 32 + j];
#pragma unroll
      for (int x = 0; x < 4; ++x) {
        float4 w = *(const float4*)(Wt_out + (kh * 128 + j * 4 + x) * 128 + c0);
#pragma unroll
        for (int a = 0; a < 6; ++a) {
          const float yx = (x == 0) ? yv[a].x : (x == 1) ? yv[a].y : (x == 2) ? yv[a].z : yv[a].w;
          acc[a].x = fmaf(yx, w.x, acc[a].x);
          acc[a].y = fmaf(yx, w.y, acc[a].y);
          acc[a].z = fmaf(yx, w.z, acc[a].z);
          acc[a].w = fmaf(yx, w.w, acc[a].w);
        }
      }
    }
    if (kh) {
#pragma unroll
      for (int a = 0; a < 6; ++a) *(float4*)(h_s + (t0 + a) * DM + c0) = acc[a];
    }
    __syncthreads();
    if (!kh) {
#pragma unroll
      for (int a = 0; a < 6; ++a) {
        float4* p = (float4*)(h_s + (t0 + a) * DM + c0);
        float4 o = *p;
        o.x += acc[a].x; o.y += acc[a].y; o.z += acc[a].z; o.w += acc[a].w;
        *p = o;
      }
    }
  } else {
    const int cg = tid & 15, tg = (tid >> 4) & 7, kh = tid >> 7;
    const int c0 = cg * 8, t0 = tg * 3;
    float acc[3][8];
#pragma unroll
    for (int a = 0; a < 3; ++a)
#pragma unroll
      for (int b = 0; b < 8; ++b) acc[a][b] = 0.f;
    const float4* y4 = (const float4*)y_s;
#pragma unroll 4
    for (int j = 0; j < 32; ++j) {
      float4 yv[3];
#pragma unroll
      for (int a = 0; a < 3; ++a) yv[a] = y4[(t0 + a) * 64 + kh * 32 + j];
#pragma unroll
      for (int b = 0; b < 8; ++b) {
        float4 w = *(const float4*)(Wout + (c0 + b) * DI + kh * 128 + j * 4);
#pragma unroll
        for (int a = 0; a < 3; ++a) {
          acc[a][b] = fmaf(yv[a].x, w.x, acc[a][b]);
          acc[a][b] = fmaf(yv[a].y, w.y, acc[a][b]);
          acc[a][b] = fmaf(yv[a].z, w.z, acc[a][b]);
          acc[a][b] = fmaf(yv[a].w, w.w, acc[a][b]);
        }
      }
    }
    if (kh) {
#pragma unroll
      for (int a = 0; a < 3; ++a) {
        float4* dst = (float4*)(h_s + (t0 + a) * DM + c0);
        dst[0] = make_float4(acc[a][0], acc[a][1], acc[a][2], acc[a][3]);
        dst[1] = make_float4(acc[a][4], acc[a][5], acc[a][6], acc[a][7]);
      }
    }
    __syncthreads();
    if (!kh) {
#pragma unroll
      for (int a = 0; a < 3; ++a)
#pragma unroll
        for (int b = 0; b < 8; ++b) h_s[(t0 + a) * DM + c0 + b] += acc[a][b];
    }
  }
  __syncthreads();

  // ---- LN2 + residual ----
#pragma unroll
  for (int i = 0; i < 6; ++i) {
    const int t = wv + 4 * i;
    const float o0 = h_s[t * DM + lane], o1 = h_s[t * DM + lane + 64];
    float s1 = o0 + o1, s2 = o0 * o0 + o1 * o1;
#pragma unroll
    for (int off = 32; off; off >>= 1) {
      s1 += __shfl_xor(s1, off, 64);
      s2 += __shfl_xor(s2, off, 64);
    }
    const float m = s1 * (1.f / DM);
    const float r = rsqrtf(s2 * (1.f / DM) - m * m + EPSV);
    const float* xr = xbase + (size_t)t * NTOK * DM;
    float* orow = out + (((size_t)bb * TT + t) * NTOK + nn) * DM;
    orow[lane] = (o0 - m) * r * g2[lane] + b2[lane] + xr[lane];
    orow[lane + 64] = (o1 - m) * r * g2[lane + 64] + b2[lane + 64] + xr[lane + 64];
  }
}

// one-shot weight transpose into workspace
__global__ void transpose_w(const float* __restrict__ Wi, const float* __restrict__ Wo,
                            float* __restrict__ wt) {
  const int i = blockIdx.x * 256 + threadIdx.x;
  if (i < 512 * 128) {            // Wt_in [128][512] <- Win [512][128]
    const int r = i & 511, c = i >> 9;
    wt[i] = Wi[r * 128 + c];
  }
  if (i < 256 * 128) {            // Wt_out [256][128] <- Wout [128][256]
    const int d = i >> 7, r = i & 127;
    wt[512 * 128 + i] = Wo[r * 256 + d];
  }
}

extern "C" void kernel_launch(void* const* d_in, const int* in_sizes, int n_in,
                              void* d_out, int out_size, void* d_ws, size_t ws_size,
                              hipStream_t stream) {
  const bool tw = ws_size >= (size_t)(512 * 128 + 256 * 128) * sizeof(float);
  if (tw) {
    transpose_w<<<dim3(256), dim3(256), 0, stream>>>(
        (const float*)d_in[3], (const float*)d_in[18], (float*)d_ws);
    bimamba<true><<<dim3(NSEQ), dim3(256), 0, stream>>>(
        (const float*)d_in[0], (const float*)d_in[1], (const float*)d_in[2],
        (const float*)d_in[3], (const float*)d_in[4], (const float*)d_in[5],
        (const float*)d_in[6], (const float*)d_in[7], (const float*)d_in[8],
        (const float*)d_in[9], (const float*)d_in[10], (const float*)d_in[11],
        (const float*)d_in[12], (const float*)d_in[13], (const float*)d_in[14],
        (const float*)d_in[15], (const float*)d_in[16], (const float*)d_in[17],
        (const float*)d_in[18], (const float*)d_in[19], (const float*)d_in[20],
        (const float*)d_ws, (float*)d_out);
  } else {
    bimamba<false><<<dim3(NSEQ), dim3(256), 0, stream>>>(
        (const float*)d_in[0], (const float*)d_in[1], (const float*)d_in[2],
        (const float*)d_in[3], (const float*)d_in[4], (const float*)d_in[5],
        (const float*)d_in[6], (const float*)d_in[7], (const float*)d_in[8],
        (const float*)d_in[9], (const float*)d_in[10], (const float*)d_in[11],
        (const float*)d_in[12], (const float*)d_in[13], (const float*)d_in[14],
        (const float*)d_in[15], (const float*)d_in[16], (const float*)d_in[17],
        (const float*)d_in[18], (const float*)d_in[19], (const float*)d_in[20],
        nullptr, (float*)d_out);
  }
}